// Round 11
// baseline (289.490 us; speedup 1.0000x reference)
//
#include <hip/hip_runtime.h>

// 3x3 conv, stride 1, pad 1, NCHW/OIHW fp32. N=16, C=32, OC=32, H=W=256.
//
// R12: direct-global implicit GEMM -- ZERO LDS, ZERO barriers.
//  Evidence: R9 ablation (read-only ~25us, write-only ~25us, full 84us =
//  super-additive) + R11 (free-run barriers null) + no pipe >37% ->
//  latency-bound staging structure, not a BW wall (R10 sustained 3.0 TB/s).
//  Kill the structure: tap displacements are (kh-1)*1024B + (kw-1)*4B ->
//  all 9 taps are compile-time imm offsets on ONE per-lane base address.
//  Each wave = one 32x32 (oc x w) output tile:
//   - A-frags: 18 coalesced 16B loads from prepped weight image (d_ws),
//     layout [t9][half][qd][oc][j] -> lane reads its frag contiguously.
//   - B-frags: per (half,j) one voffset; 9 imm-offset dword loads (2x128B
//     coalesced); L1 serves kw re-reads, L2/L3 serve kh/halo (x L3-fits).
//   - 18 MFMA 32x32x16 per tile; plain (cached) stores, L2 merges lines.
//  Same verified A/B/D lane mappings + cvtpk RNE as R5/R7/R11; only the
//  data path changed. h-edges: uniform tap skip. w-edge lanes: +-1 dword
//  address bias + value mask (in-bounds proven: min idx 0, max = last elem).
//  VGPR ~85 -> ~6 waves/SIMD; every load issuable immediately; no coupling.

constexpr int N_  = 16;
constexpr int C_  = 32;
constexpr int OC_ = 32;
constexpr int H_  = 256;
constexpr int W_  = 256;
constexpr int HW_ = H_ * W_;

constexpr int WGROUPS = 36 * 32;          // (t9 x half x qd) x oc
constexpr int WBYTES  = WGROUPS * 16;     // 18432 B prepped weight image

typedef __attribute__((ext_vector_type(8)))  short short8v;
typedef __attribute__((ext_vector_type(4)))  int   int4v;
typedef __attribute__((ext_vector_type(16))) float float16v;

// one instruction: dst.lo16 = bf16(lo), dst.hi16 = bf16(hi) (RNE)
static __device__ __forceinline__ unsigned cvtpk(float lo, float hi) {
    unsigned r;
    asm("v_cvt_pk_bf16_f32 %0, %1, %2" : "=v"(r) : "v"(lo), "v"(hi));
    return r;
}

static __device__ __forceinline__ short8v pack8(float v0, float v1, float v2, float v3,
                                                float v4, float v5, float v6, float v7) {
    int4v iv;
    iv.x = (int)cvtpk(v0, v1);
    iv.y = (int)cvtpk(v2, v3);
    iv.z = (int)cvtpk(v4, v5);
    iv.w = (int)cvtpk(v6, v7);
    return __builtin_bit_cast(short8v, iv);
}

// ---- prep: weight image [t9][half][qd][oc][j] as bf16, 16B per (g) ----
// main kernel lane (col=oc, qd) reads group g = ((t9*2+half)*2+qd)*32+oc
// as int4 = 8 bf16 = w[oc][ic = half*16+qd*8+j][t9], j=0..7.
__global__ void conv_w_prep(const float* __restrict__ wgt,
                            unsigned* __restrict__ wp) {
    const int g = blockIdx.x * 256 + threadIdx.x;
    if (g >= WGROUPS) return;
    const int oc  = g & 31;
    const int q   = g >> 5;          // 0..35
    const int qd  = q & 1;
    const int hf  = (q >> 1) & 1;
    const int t9  = q >> 2;
    const int icb = hf * 16 + qd * 8;
    float v[8];
    #pragma unroll
    for (int j = 0; j < 8; ++j) v[j] = wgt[(oc * 32 + icb + j) * 9 + t9];
    wp[g * 4 + 0] = cvtpk(v[0], v[1]);
    wp[g * 4 + 1] = cvtpk(v[2], v[3]);
    wp[g * 4 + 2] = cvtpk(v[4], v[5]);
    wp[g * 4 + 3] = cvtpk(v[6], v[7]);
}

template<bool USE_WS>
__global__ __launch_bounds__(256) void conv3x3_mfma_kernel(
    const float* __restrict__ x,     // [N][C][H][W]
    const float* __restrict__ wgt,   // [OC][C][3][3]
    const float* __restrict__ bias,  // [OC]
    const unsigned* __restrict__ wpk,  // prepped weights (d_ws)
    float* __restrict__ out)         // [N][OC][H][W]
{
    const int tid = threadIdx.x;

    // XCD swizzle: 8192 blocks, 8 XCDs x 1024 consecutive (bijective).
    // Consecutive same-XCD blocks cover the same/adjacent h -> row reuse in L2.
    const int id = blockIdx.x;
    const int L  = (id & 7) * 1024 + (id >> 3);
    const int n  = L >> 9;           // image 0..15
    const int r9 = L & 511;
    const int h  = r9 >> 1;          // output row
    const int side = r9 & 1;         // w half: 0 -> w 0..127, 1 -> 128..255

    const int lane = tid & 63;
    const int wv   = tid >> 6;       // wave 0..3
    const int col  = lane & 31;      // A: oc; B/D: w col
    const int qd   = lane >> 5;      // k-quad select
    const int w0   = side * 128 + wv * 32;
    const int wc   = w0 + col;       // this lane's w column

    // w-edge handling: bias address +-1 dword so the (masked) load stays
    // in-bounds; value is zeroed by the mask.
    const int  left0  = (wc == 0)      ? 1 : 0;
    const int  right0 = (wc == W_ - 1) ? -1 : 0;
    const bool mL = (wc > 0);
    const bool mR = (wc < W_ - 1);

    // acc init with bias (D: row=oc=(r&3)+8*(r>>2)+4*qd, col=w; verified R2)
    float16v acc;
    #pragma unroll
    for (int r = 0; r < 16; ++r)
        acc[r] = bias[(r & 3) + 8 * (r >> 2) + 4 * qd];

    const unsigned bidx = (unsigned)(n * C_ * HW_ + h * W_ + wc);

    #pragma unroll
    for (int hf = 0; hf < 2; ++hf) {
        // ---- A fragments for this ic-half: 9 coalesced 16B loads ----
        short8v af[9];
        if (USE_WS) {
            #pragma unroll
            for (int t9 = 0; t9 < 9; ++t9) {
                const int g = ((t9 * 2 + hf) * 2 + qd) * 32 + col;
                af[t9] = __builtin_bit_cast(short8v,
                             *(const int4v*)(wpk + (size_t)g * 4));
            }
        } else {
            // fallback (no workspace): per-lane gather from OIHW
            const int icb = hf * 16 + qd * 8;
            #pragma unroll
            for (int t9 = 0; t9 < 9; ++t9) {
                float v[8];
                #pragma unroll
                for (int j = 0; j < 8; ++j)
                    v[j] = wgt[(col * 32 + icb + j) * 9 + t9];
                af[t9] = pack8(v[0], v[1], v[2], v[3], v[4], v[5], v[6], v[7]);
            }
        }

        // ---- per-j voffsets (dwords); taps are imm offsets on these ----
        unsigned vo[8];
        #pragma unroll
        for (int j = 0; j < 8; ++j)
            vo[j] = bidx + (unsigned)((hf * 16 + qd * 8 + j) * HW_);

        #pragma unroll
        for (int kh = 0; kh < 3; ++kh) {
            if (kh == 0 && h == 0)      continue;   // uniform: top pad row
            if (kh == 2 && h == H_ - 1) continue;   // uniform: bottom pad row
            #pragma unroll
            for (int kw = 0; kw < 3; ++kw) {
                const int abias = (kw == 0) ? 1 : ((kw == 2) ? -1 : 0);
                float bv[8];
                #pragma unroll
                for (int j = 0; j < 8; ++j) {
                    const float* p = x + vo[j]
                        + ((kw == 0) ? left0 : ((kw == 2) ? right0 : 0));
                    // compile-time tap displacement -> signed imm offset
                    bv[j] = p[(kh - 1) * W_ + (kw - 1)];
                }
                if (kw == 0) {
                    #pragma unroll
                    for (int j = 0; j < 8; ++j) bv[j] = mL ? bv[j] : 0.f;
                } else if (kw == 2) {
                    #pragma unroll
                    for (int j = 0; j < 8; ++j) bv[j] = mR ? bv[j] : 0.f;
                }
                (void)abias;
                const short8v bf = pack8(bv[0], bv[1], bv[2], bv[3],
                                         bv[4], bv[5], bv[6], bv[7]);
                acc = __builtin_amdgcn_mfma_f32_32x32x16_bf16(
                          af[kh * 3 + kw], bf, acc, 0, 0, 0);
            }
        }
    }

    // ---- epilogue: plain cached stores; L2 write-back merges lines ----
    const size_t outb = (size_t)n * OC_ * HW_ + (size_t)h * W_ + wc;
    #pragma unroll
    for (int r = 0; r < 16; ++r) {
        const int oc = (r & 3) + 8 * (r >> 2) + 4 * qd;
        out[outb + (size_t)oc * HW_] = acc[r];
    }
}

extern "C" void kernel_launch(void* const* d_in, const int* in_sizes, int n_in,
                              void* d_out, int out_size, void* d_ws, size_t ws_size,
                              hipStream_t stream) {
    const float* x    = (const float*)d_in[0];
    const float* wgt  = (const float*)d_in[1];
    const float* bias = (const float*)d_in[2];
    float* out        = (float*)d_out;

    dim3 grid(N_ * H_ * 2);   // 8192 blocks: one per (n, h, w-half)
    dim3 block(256);          // 4 waves, each a 32x32 (oc x w) tile

    if (d_ws != nullptr && ws_size >= (size_t)WBYTES) {
        unsigned* wp = (unsigned*)d_ws;
        conv_w_prep<<<dim3(5), dim3(256), 0, stream>>>(wgt, wp);
        conv3x3_mfma_kernel<true><<<grid, block, 0, stream>>>(x, wgt, bias, wp, out);
    } else {
        conv3x3_mfma_kernel<false><<<grid, block, 0, stream>>>(x, wgt, bias, nullptr, out);
    }
}